// Round 8
// baseline (363.333 us; speedup 1.0000x reference)
//
#include <hip/hip_runtime.h>

typedef unsigned short ushort_t;
typedef __attribute__((ext_vector_type(8))) short short8;
typedef __attribute__((ext_vector_type(8))) __bf16 bf16x8;
typedef __attribute__((ext_vector_type(4))) float float4v;
typedef __attribute__((ext_vector_type(4))) unsigned int uint4v;

// ---------- bf16 helpers ----------
__device__ __forceinline__ float bf2f(ushort_t u) {
    unsigned int v = ((unsigned int)u) << 16;
    return __builtin_bit_cast(float, v);
}
__device__ __forceinline__ ushort_t f2bf(float f) {
    unsigned int u = __builtin_bit_cast(unsigned int, f);
    unsigned int lsb = (u >> 16) & 1u;
    u += 0x7fffu + lsb;  // round-to-nearest-even
    return (ushort_t)(u >> 16);
}
__device__ __forceinline__ uint4v pack8(const ushort_t* r) {
    uint4v u;
#pragma unroll
    for (int i = 0; i < 4; ++i)
        u[i] = (unsigned int)r[2 * i] | ((unsigned int)r[2 * i + 1] << 16);
    return u;
}
__device__ __forceinline__ void unpack8(uint4v u, float* f) {
#pragma unroll
    for (int i = 0; i < 4; ++i) {
        unsigned int x = u[i];
        f[2 * i] = __builtin_bit_cast(float, x << 16);
        f[2 * i + 1] = __builtin_bit_cast(float, x & 0xffff0000u);
    }
}
__device__ __forceinline__ uint4v ld8f32_bf(const float* p) {
    float4v a = *(const float4v*)p;
    float4v b = *(const float4v*)(p + 4);
    ushort_t r[8];
#pragma unroll
    for (int j = 0; j < 4; ++j) { r[j] = f2bf(a[j]); r[4 + j] = f2bf(b[j]); }
    return pack8(r);
}

// ---------- async global->LDS (16B per lane, dest = uniform base + lane*16) ----------
#if __has_builtin(__builtin_amdgcn_global_load_lds)
#define HAVE_GLDS 1
__device__ __forceinline__ void glds16(const ushort_t* gp, ushort_t* lp) {
    __builtin_amdgcn_global_load_lds((const __attribute__((address_space(1))) void*)gp,
                                     (__attribute__((address_space(3))) void*)lp, 16, 0, 0);
}
#else
#define HAVE_GLDS 0
#endif

// ---------- MFMA hedge ----------
template <typename V>
__device__ __forceinline__ auto mfma_sel(V a, V b, float4v c, int)
    -> decltype(__builtin_amdgcn_mfma_f32_16x16x32_bf16(a, b, c, 0, 0, 0)) {
    return __builtin_amdgcn_mfma_f32_16x16x32_bf16(a, b, c, 0, 0, 0);
}
template <typename V>
__device__ __forceinline__ float4v mfma_sel(V a, V b, float4v c, long) {
    return __builtin_amdgcn_mfma_f32_16x16x32_bf16(__builtin_bit_cast(bf16x8, a),
                                                   __builtin_bit_cast(bf16x8, b), c, 0, 0, 0);
}
__device__ __forceinline__ float4v mfma_bf16(short8 a, short8 b, float4v c) {
    return mfma_sel(a, b, c, 0);
}

__device__ __forceinline__ float wave_sum(float v) {
#pragma unroll
    for (int o = 32; o; o >>= 1) v += __shfl_xor(v, o);
    return v;
}

// ---------- constants ----------
#define HIDDEN 2880
#define NTOK 2048
#define QKV_DIM 5120
#define ATTN_DIM 4096
#define SM_SCALE 0.125f

// YaRN rope constants (shared by attn fused rope)
#define ROPE_STEP 0.37244970540869975f   /* 11.918390573078392 / 32 */
#define ROPE_CONC 1.3465735902799727f
#define ROPE_LOW 8.092890725542669f
#define ROPE_INVDEN 0.10745959154836568f /* 1 / 9.305804387286162 */

__device__ __forceinline__ float rope_invfreq(int j) {
    float invf = __expf(-(float)j * ROPE_STEP);
    float ramp = ((float)j - ROPE_LOW) * ROPE_INVDEN;
    float mask = 1.f - fminf(fmaxf(ramp, 0.f), 1.f);
    return invf * ((1.f - mask) * 0.03125f + mask);
}

// ---------- prep: rmsnorm (blocks 0..2047) + fp32->bf16 weight convert (rest) ----------
__global__ __launch_bounds__(256) void prep_kernel(const float* __restrict__ x,
                                                   const float* __restrict__ wgt,
                                                   ushort_t* __restrict__ tout,
                                                   const float* __restrict__ a,
                                                   ushort_t* __restrict__ ao, int na8,
                                                   const float* __restrict__ b,
                                                   ushort_t* __restrict__ bo, int nb8) {
    const int tid = threadIdx.x;
    __shared__ float red[4];
    if (blockIdx.x < NTOK) {
        // ---- RMSNorm for token blockIdx.x ----
        const int tok = blockIdx.x;
        const float* xr = x + (size_t)tok * HIDDEN;
        float v[16];
        float ss = 0.f;
#pragma unroll
        for (int i = 0; i < 2; ++i) {
            int c = tid + i * 256;
            if (c < 360) {
                float4v va = *(const float4v*)(xr + c * 8);
                float4v vb = *(const float4v*)(xr + c * 8 + 4);
#pragma unroll
                for (int j = 0; j < 4; ++j) { v[i * 8 + j] = va[j]; v[i * 8 + 4 + j] = vb[j]; }
#pragma unroll
                for (int j = 0; j < 8; ++j) ss += v[i * 8 + j] * v[i * 8 + j];
            }
        }
        ss = wave_sum(ss);
        if ((tid & 63) == 0) red[tid >> 6] = ss;
        __syncthreads();
        float scale = rsqrtf((red[0] + red[1] + red[2] + red[3]) * (1.f / 2880.f) + 1e-5f);
#pragma unroll
        for (int i = 0; i < 2; ++i) {
            int c = tid + i * 256;
            if (c < 360) {
                float4v wa = *(const float4v*)(wgt + c * 8);
                float4v wb = *(const float4v*)(wgt + c * 8 + 4);
                ushort_t r[8];
#pragma unroll
                for (int j = 0; j < 4; ++j) {
                    r[j] = f2bf(v[i * 8 + j] * scale * wa[j]);
                    r[4 + j] = f2bf(v[i * 8 + 4 + j] * scale * wb[j]);
                }
                *(uint4v*)(tout + (size_t)tok * HIDDEN + c * 8) = pack8(r);
            }
        }
    } else {
        // ---- weight conversion ----
        int idx = (blockIdx.x - NTOK) * 256 + tid;
        if (idx < na8) {
            *(uint4v*)(ao + (size_t)idx * 8) = ld8f32_bf(a + (size_t)idx * 8);
        } else {
            int j = idx - na8;
            if (j < nb8) *(uint4v*)(bo + (size_t)j * 8) = ld8f32_bf(b + (size_t)j * 8);
        }
    }
}

// ---------- RMSNorm standalone (fallback path) ----------
__global__ __launch_bounds__(256) void rmsnorm_kernel(const float* __restrict__ x,
                                                      const float* __restrict__ wgt,
                                                      ushort_t* __restrict__ out) {
    const int tok = blockIdx.x, tid = threadIdx.x;
    const float* xr = x + (size_t)tok * HIDDEN;
    float v[16];
    float ss = 0.f;
#pragma unroll
    for (int i = 0; i < 2; ++i) {
        int c = tid + i * 256;
        if (c < 360) {
            float4v a = *(const float4v*)(xr + c * 8);
            float4v b = *(const float4v*)(xr + c * 8 + 4);
#pragma unroll
            for (int j = 0; j < 4; ++j) { v[i * 8 + j] = a[j]; v[i * 8 + 4 + j] = b[j]; }
#pragma unroll
            for (int j = 0; j < 8; ++j) ss += v[i * 8 + j] * v[i * 8 + j];
        }
    }
    ss = wave_sum(ss);
    __shared__ float red[4];
    if ((tid & 63) == 0) red[tid >> 6] = ss;
    __syncthreads();
    float scale = rsqrtf((red[0] + red[1] + red[2] + red[3]) * (1.f / 2880.f) + 1e-5f);
#pragma unroll
    for (int i = 0; i < 2; ++i) {
        int c = tid + i * 256;
        if (c < 360) {
            float4v wa = *(const float4v*)(wgt + c * 8);
            float4v wb = *(const float4v*)(wgt + c * 8 + 4);
            ushort_t r[8];
#pragma unroll
            for (int j = 0; j < 4; ++j) {
                r[j] = f2bf(v[i * 8 + j] * scale * wa[j]);
                r[4 + j] = f2bf(v[i * 8 + 4 + j] * scale * wb[j]);
            }
            *(uint4v*)(out + (size_t)tok * HIDDEN + c * 8) = pack8(r);
        }
    }
}

// ---------- GEMM: C[M,N] = A[M,K](bf16) @ B[N,K]^T + bias (+ resid) ----------
// Blocks: flattened id XCD-swizzled (T1, bijective since nwg%8==0 for all grids here).
// Grid-residency rule (r3): at 2 blocks/CU capacity, prefer grids just under 512.
// LDS-BW model (r5/r7): per wave per K-step, ds_read bytes = (4+NI) KB x2; NI=3 is
//   LDS-read-bound. BREG attacks this: B-fragments are loaded straight from global
//   into double-buffered REGISTERS (per-lane 16B contiguous; B slice per XCD ~3MB
//   fits per-XCD L2 under the swizzle; wn-duplicate waves hit L1). LDS traffic/wave
//   drops 14->8 KB, Bs LDS freed. Issued alongside the A-glds, drained by the SAME
//   single barrier - schedule shape unchanged (r2's extra-wait regression avoided).
//   kt-loop unrolled x2 so breg indexing is static (rule #20); requires nk even.
// NOTE (r7 compile lesson): HAVE_GLDS differs between host and device compilation
//   passes (__has_builtin of a device builtin is false on host). Never static_assert
//   on it; derive USE_BREG = BREG && GL so the host pass degrades to the fallback.
// GL path: double-buffered LDS, ONE barrier per K-iter (proven schedule). Counted-
//   vmcnt 2-barrier variant measured -17% (r2) - do not reintroduce.
//   XOR chunk swizzle (p = c ^ (row&7)) -> 0 bank conflicts.
template <int BN, bool RESID, bool OUTF32, bool BF16B, bool BREG = false>
__global__ __launch_bounds__(256) void gemm_kernel(const ushort_t* __restrict__ A,
                                                   const void* __restrict__ B,
                                                   const float* __restrict__ bias,
                                                   const float* __restrict__ resid,
                                                   void* __restrict__ Cout, int M, int N, int K) {
    constexpr int BM = 128, BK = 64;
    constexpr bool GL = BF16B && (HAVE_GLDS != 0);
    constexpr bool USE_BREG = BREG && GL;  // host pass: GL=false -> full fallback
    constexpr int LDT = GL ? 64 : 72;
    constexpr int NBUF = GL ? 2 : 1;
    static_assert(BN == 160 || BN == 128 || BN == 96 || BN == 64, "");
    constexpr int BS_ELEMS = USE_BREG ? 8 : BN * LDT;  // Bs unused under BREG
    __shared__ __align__(16) ushort_t As[NBUF][BM * LDT];
    __shared__ __align__(16) ushort_t Bs[NBUF][BS_ELEMS];

    // XCD-aware chunked swizzle of the flattened block id (nwg % 8 == 0 for all grids)
    const int nbx = gridDim.x;
    int wg = blockIdx.y * nbx + blockIdx.x;
    {
        const int nwg = nbx * gridDim.y;
        const int cpx = nwg >> 3;
        wg = (wg & 7) * cpx + (wg >> 3);
    }
    const int m0 = (wg / nbx) * BM;
    const int n0 = (wg % nbx) * BN;
    const int tid = threadIdx.x;
    const int w = tid >> 6, lane = tid & 63;
    const int quad = lane >> 4, l16 = lane & 15;

    constexpr int WN = BN / 2;
    constexpr int NI = WN / 16;  // 5 / 4 / 3 / 2
    const int wm = (w >> 1) * 64;
    const int wn = (w & 1) * WN;

    float4v acc[4][NI];
#pragma unroll
    for (int i = 0; i < 4; ++i)
#pragma unroll
        for (int j = 0; j < NI; ++j) acc[i][j] = (float4v){0.f, 0.f, 0.f, 0.f};

    const int nk = K / BK;

#if HAVE_GLDS
    if constexpr (USE_BREG) {
        // ---- A via glds double-buffer; B direct global -> static double-buffered regs ----
        constexpr int NAI = BM / 32;
        const ushort_t* Bp = (const ushort_t*)B;
        const ushort_t* agp[NAI];
        ushort_t* alp[2][NAI];
#pragma unroll
        for (int i = 0; i < NAI; ++i) {
            int sb = (w * NAI + i) * 64;
            int s = sb + lane, r = s >> 3, p = s & 7, c = p ^ (r & 7);
            agp[i] = A + (size_t)(m0 + r) * K + c * 8;
            alp[0][i] = &As[0][sb * 8];
            alp[1][i] = &As[1][sb * 8];
        }
        // B row base pointers: row = n0 + wn + ni*16 + l16, col base = quad*8
        const ushort_t* brow[NI];
#pragma unroll
        for (int ni = 0; ni < NI; ++ni)
            brow[ni] = Bp + (size_t)(n0 + wn + ni * 16 + l16) * K + quad * 8;

        uint4v bregA[2][NI], bregB[2][NI];  // [ks][ni], two static K-iter sets

#define LOAD_B(dst, ktv)                                                       \
    {                                                                          \
        const int kb = (ktv) * BK;                                             \
        _Pragma("unroll") for (int ks = 0; ks < 2; ++ks)                       \
            _Pragma("unroll") for (int ni = 0; ni < NI; ++ni)                  \
                dst[ks][ni] = *(const uint4v*)(brow[ni] + kb + ks * 32);       \
    }
#define COMPUTE_TILE(bufi, bsrc)                                               \
    {                                                                          \
        const ushort_t* Asb = As[bufi];                                        \
        _Pragma("unroll") for (int ks = 0; ks < 2; ++ks) {                     \
            short8 af[4], bfr[NI];                                             \
            _Pragma("unroll") for (int mi = 0; mi < 4; ++mi) {                 \
                int row = wm + mi * 16 + l16;                                  \
                af[mi] = *(const short8*)(Asb + row * LDT +                    \
                                          (((ks * 4 + quad) ^ (row & 7)) * 8));\
            }                                                                  \
            _Pragma("unroll") for (int ni = 0; ni < NI; ++ni)                  \
                bfr[ni] = __builtin_bit_cast(short8, bsrc[ks][ni]);            \
            _Pragma("unroll") for (int mi = 0; mi < 4; ++mi)                   \
                _Pragma("unroll") for (int ni = 0; ni < NI; ++ni)              \
                    acc[mi][ni] = mfma_bf16(af[mi], bfr[ni], acc[mi][ni]);     \
        }                                                                      \
    }

        // prologue: tile 0 -> buf0 + bregA
#pragma unroll
        for (int i = 0; i < NAI; ++i) glds16(agp[i], alp[0][i]);
        LOAD_B(bregA, 0);
        __syncthreads();

        for (int kt = 0; kt < nk; kt += 2) {  // nk even (K=4096/64)
            // step A: compute tile kt from buf0/bregA; prefetch kt+1 -> buf1/bregB
            if (kt + 1 < nk) {
                LOAD_B(bregB, kt + 1);
                const int k0 = (kt + 1) * BK;
#pragma unroll
                for (int i = 0; i < NAI; ++i) glds16(agp[i] + k0, alp[1][i]);
            }
            COMPUTE_TILE(0, bregA);
            __syncthreads();
            // step B: compute tile kt+1 from buf1/bregB; prefetch kt+2 -> buf0/bregA
            if (kt + 2 < nk) {
                LOAD_B(bregA, kt + 2);
                const int k0 = (kt + 2) * BK;
#pragma unroll
                for (int i = 0; i < NAI; ++i) glds16(agp[i] + k0, alp[0][i]);
            }
            COMPUTE_TILE(1, bregB);
            __syncthreads();
        }
#undef LOAD_B
#undef COMPUTE_TILE
    } else if constexpr (GL) {
        constexpr int NAI = BM / 32;  // glds issues per wave for A
        constexpr int NBI = BN / 32;  // glds issues per wave for B
        const ushort_t* Bp = (const ushort_t*)B;
        const ushort_t* agp[NAI];
        const ushort_t* bgp[NBI];
        ushort_t* alp[2][NAI];
        ushort_t* blp[2][NBI];
#pragma unroll
        for (int i = 0; i < NAI; ++i) {
            int sb = (w * NAI + i) * 64;
            int s = sb + lane, r = s >> 3, p = s & 7, c = p ^ (r & 7);
            agp[i] = A + (size_t)(m0 + r) * K + c * 8;
            alp[0][i] = &As[0][sb * 8];
            alp[1][i] = &As[1][sb * 8];
        }
#pragma unroll
        for (int i = 0; i < NBI; ++i) {
            int sb = (w * NBI + i) * 64;
            int s = sb + lane, r = s >> 3, p = s & 7, c = p ^ (r & 7);
            bgp[i] = Bp + (size_t)(n0 + r) * K + c * 8;
            blp[0][i] = &Bs[0][sb * 8];
            blp[1][i] = &Bs[1][sb * 8];
        }
        // prologue: tile 0 -> buf 0
#pragma unroll
        for (int i = 0; i < NAI; ++i) glds16(agp[i], alp[0][i]);
#pragma unroll
        for (int i = 0; i < NBI; ++i) glds16(bgp[i], blp[0][i]);
        __syncthreads();

        for (int kt = 0; kt < nk; ++kt) {
            const int cur = kt & 1;
            if (kt + 1 < nk) {
                const int k0 = (kt + 1) * BK;
#pragma unroll
                for (int i = 0; i < NAI; ++i) glds16(agp[i] + k0, alp[cur ^ 1][i]);
#pragma unroll
                for (int i = 0; i < NBI; ++i) glds16(bgp[i] + k0, blp[cur ^ 1][i]);
            }
            const ushort_t* Asb = As[cur];
            const ushort_t* Bsb = Bs[cur];
#pragma unroll
            for (int ks = 0; ks < 2; ++ks) {
                short8 af[4], bfr[NI];
#pragma unroll
                for (int mi = 0; mi < 4; ++mi) {
                    int row = wm + mi * 16 + l16;
                    af[mi] = *(const short8*)(Asb + row * LDT + ((ks * 4 + quad) ^ (row & 7)) * 8);
                }
#pragma unroll
                for (int ni = 0; ni < NI; ++ni) {
                    int row = wn + ni * 16 + l16;
                    bfr[ni] = *(const short8*)(Bsb + row * LDT + ((ks * 4 + quad) ^ (row & 7)) * 8);
                }
#pragma unroll
                for (int mi = 0; mi < 4; ++mi)
#pragma unroll
                    for (int ni = 0; ni < NI; ++ni)
                        acc[mi][ni] = mfma_bf16(af[mi], bfr[ni], acc[mi][ni]);
            }
            __syncthreads();
        }
    } else
#endif
    {
        // fallback: padded LDS + register prefetch (round-5 structure)
        constexpr int ACH = BM * BK / 8 / 256;
        constexpr int BCH = BN * BK / 8 / 256;
        uint4v areg[ACH], breg[BCH];
#pragma unroll
        for (int i = 0; i < ACH; ++i) {
            int c = tid + i * 256, r = c >> 3, col = c & 7;
            areg[i] = *(const uint4v*)(A + (size_t)(m0 + r) * K + col * 8);
        }
#pragma unroll
        for (int i = 0; i < BCH; ++i) {
            int c = tid + i * 256, r = c >> 3, col = c & 7;
            if constexpr (BF16B)
                breg[i] = *(const uint4v*)((const ushort_t*)B + (size_t)(n0 + r) * K + col * 8);
            else
                breg[i] = ld8f32_bf((const float*)B + (size_t)(n0 + r) * K + col * 8);
        }
        for (int kt = 0; kt < nk; ++kt) {
            __syncthreads();
#pragma unroll
            for (int i = 0; i < ACH; ++i) {
                int c = tid + i * 256, r = c >> 3, col = c & 7;
                *(uint4v*)(&As[0][r * LDT + col * 8]) = areg[i];
            }
#pragma unroll
            for (int i = 0; i < BCH; ++i) {
                int c = tid + i * 256, r = c >> 3, col = c & 7;
                *(uint4v*)(&Bs[0][(size_t)r * LDT + col * 8]) = breg[i];
            }
            __syncthreads();
            if (kt + 1 < nk) {
                const int k0 = (kt + 1) * BK;
#pragma unroll
                for (int i = 0; i < ACH; ++i) {
                    int c = tid + i * 256, r = c >> 3, col = c & 7;
                    areg[i] = *(const uint4v*)(A + (size_t)(m0 + r) * K + k0 + col * 8);
                }
#pragma unroll
                for (int i = 0; i < BCH; ++i) {
                    int c = tid + i * 256, r = c >> 3, col = c & 7;
                    if constexpr (BF16B)
                        breg[i] = *(const uint4v*)((const ushort_t*)B + (size_t)(n0 + r) * K + k0 + col * 8);
                    else
                        breg[i] = ld8f32_bf((const float*)B + (size_t)(n0 + r) * K + k0 + col * 8);
                }
            }
#pragma unroll
            for (int ks = 0; ks < 2; ++ks) {
                short8 af[4], bfr[NI];
#pragma unroll
                for (int mi = 0; mi < 4; ++mi)
                    af[mi] = *(const short8*)(&As[0][(wm + mi * 16 + l16) * LDT + ks * 32 + quad * 8]);
#pragma unroll
                for (int ni = 0; ni < NI; ++ni)
                    bfr[ni] = *(const short8*)(&Bs[0][(size_t)(wn + ni * 16 + l16) * LDT + ks * 32 + quad * 8]);
#pragma unroll
                for (int mi = 0; mi < 4; ++mi)
#pragma unroll
                    for (int ni = 0; ni < NI; ++ni)
                        acc[mi][ni] = mfma_bf16(af[mi], bfr[ni], acc[mi][ni]);
            }
        }
    }

    // epilogue: C/D layout col = lane&15, row = quad*4 + reg
#pragma unroll
    for (int ni = 0; ni < NI; ++ni) {
        int gc = n0 + wn + ni * 16 + l16;
        float bv = bias[gc];
#pragma unroll
        for (int mi = 0; mi < 4; ++mi) {
#pragma unroll
            for (int r = 0; r < 4; ++r) {
                int gr = m0 + wm + mi * 16 + quad * 4 + r;
                float vv = acc[mi][ni][r] + bv;
                if constexpr (RESID) vv += resid[(size_t)gr * N + gc];
                if constexpr (OUTF32) ((float*)Cout)[(size_t)gr * N + gc] = vv;
                else ((ushort_t*)Cout)[(size_t)gr * N + gc] = f2bf(vv);
            }
        }
    }
}

// ---------- MFMA attention: sliding window 128 + sink, RoPE fused on load ----------
// Grid (qc 16, kvh*2+half 16, b 2) = 512 blocks, 2 blocks/CU (157.7KB LDS).
// Wave w handles head kvh*8 + half*4 + w, 4 query-tiles of 16.
// RoPE fusion (r6): qkvbuf is UN-roped; q/k regions are consumed only here.
// Window-aware compute: q-tile qtile touches key-tiles qtile..qtile+8 and PV slices
//   kt = (qtile>>1)..+4. Pair structure: q-tiles (2p,2p+1) share Vf[5][4] hoist.
__global__ __launch_bounds__(256, 2) void attn_mfma_kernel(const ushort_t* __restrict__ qkv,
                                                           const float* __restrict__ sinks,
                                                           ushort_t* __restrict__ attnbuf) {
    constexpr int LDK = 72, LDV = 200, LDP = 200;
    __shared__ __align__(16) ushort_t Ks[192 * LDK];
    __shared__ __align__(16) ushort_t Vt[64 * LDV];
    __shared__ __align__(16) ushort_t Pb[4][16 * LDP];

    const int qc = blockIdx.x, kvh = blockIdx.y >> 1, half = blockIdx.y & 1, b = blockIdx.z;
    const int tid = threadIdx.x;
    const int w = tid >> 6, lane = tid & 63;
    const int quad = lane >> 4, l16 = lane & 15;
    const int w0 = qc * 64 - 127;  // key position of LDS row 0

    // K stage + rope: 3 iters; lane owns dims [col4*8,+8) and [+32,+8) of row c>>2.
    {
        float invfK[8];
#pragma unroll
        for (int jj = 0; jj < 8; ++jj) invfK[jj] = rope_invfreq((tid & 3) * 8 + jj);
        for (int c = tid; c < 192 * 4; c += 256) {
            int row = c >> 2, col4 = c & 3;
            int pos = w0 + row;
            pos = pos < 0 ? 0 : (pos > 1023 ? 1023 : pos);
            size_t gk = ((size_t)(b * 1024 + pos)) * QKV_DIM + 4096 + kvh * 64 + col4 * 8;
            uint4v u1 = *(const uint4v*)(qkv + gk);
            uint4v u2 = *(const uint4v*)(qkv + gk + 32);
            float f1[8], f2[8];
            unpack8(u1, f1);
            unpack8(u2, f2);
            float s = (float)pos;
            ushort_t r1[8], r2[8];
#pragma unroll
            for (int jj = 0; jj < 8; ++jj) {
                float ang = s * invfK[jj];
                float cc = __cosf(ang) * ROPE_CONC;
                float sn = __sinf(ang) * ROPE_CONC;
                r1[jj] = f2bf(f1[jj] * cc - f2[jj] * sn);
                r2[jj] = f2bf(f2[jj] * cc + f1[jj] * sn);
            }
            *(uint4v*)(Ks + row * LDK + col4 * 8) = pack8(r1);
            *(uint4v*)(Ks + row * LDK + (col4 + 4) * 8) = pack8(r2);
        }
    }
    // V stage (transpose), no rope
    for (int c = tid; c < 192 * 8; c += 256) {
        int row = c >> 3, col8 = c & 7;
        int pos = w0 + row;
        pos = pos < 0 ? 0 : (pos > 1023 ? 1023 : pos);
        size_t gv = ((size_t)(b * 1024 + pos)) * QKV_DIM + 4608 + kvh * 64 + col8 * 8;
        uint4v vv = *(const uint4v*)(qkv + gv);
        ushort_t vs[8];
#pragma unroll
        for (int i = 0; i < 4; ++i) {
            vs[2 * i] = (ushort_t)(vv[i] & 0xffffu);
            vs[2 * i + 1] = (ushort_t)(vv[i] >> 16);
        }
#pragma unroll
        for (int j = 0; j < 8; ++j) Vt[(col8 * 8 + j) * LDV + row] = vs[j];
    }
    __syncthreads();

    ushort_t* Pw = Pb[w];
    const int h = kvh * 8 + half * 4 + w;
    const float sink_f = sinks[h];

    // per-lane Q rope inv_freq: j = quad*8+jj
    float invfQ[8];
#pragma unroll
    for (int jj = 0; jj < 8; ++jj) invfQ[jj] = rope_invfreq(quad * 8 + jj);

    for (int p = 0; p < 2; ++p) {  // q-tile pair: q-tiles 2p, 2p+1 share PV kt = p..p+4
        short8 Vf[5][4];
#pragma unroll
        for (int j = 0; j < 5; ++j)
#pragma unroll
            for (int nv = 0; nv < 4; ++nv)
                Vf[j][nv] = *(const short8*)(Vt + (nv * 16 + l16) * LDV + (p + j) * 32 + quad * 8);

#pragma unroll
        for (int qq = 0; qq < 2; ++qq) {
            const int qtile = 2 * p + qq;
            const int tokb = b * 1024 + qc * 64 + qtile * 16;

            // Q load + lane-local rope
            short8 qf[2];
            {
                const ushort_t* qp = qkv + ((size_t)(tokb + l16)) * QKV_DIM + h * 64 + quad * 8;
                uint4v u1 = *(const uint4v*)qp;
                uint4v u2 = *(const uint4v*)(qp + 32);
                float f1[8], f2[8];
                unpack8(u1, f1);
                unpack8(u2, f2);
                float s = (float)((tokb + l16) & 1023);
                ushort_t r1[8], r2[8];
#pragma unroll
                for (int jj = 0; jj < 8; ++jj) {
                    float ang = s * invfQ[jj];
                    float cc = __cosf(ang) * ROPE_CONC;
                    float sn = __sinf(ang) * ROPE_CONC;
                    r1[jj] = f2bf(f1[jj] * cc - f2[jj] * sn);
                    r2[jj] = f2bf(f2[jj] * cc + f1[jj] * sn);
                }
                qf[0] = __builtin_bit_cast(short8, pack8(r1));
                qf[1] = __builtin_bit_cast(short8, pack8(r2));
            }

            // QK^T over the 9 valid key-tiles (nt = qtile + j)
            float4v acc[9];
#pragma unroll
            for (int j = 0; j < 9; ++j) acc[j] = (float4v){0.f, 0.f, 0.f, 0.f};
            __builtin_amdgcn_s_setprio(1);
#pragma unroll
            for (int j = 0; j < 9; ++j) {
                const int nt = qtile + j;
#pragma unroll
                for (int ks = 0; ks < 2; ++ks) {
                    short8 kf = *(const short8*)(Ks + (nt * 16 + l16) * LDK + ks * 32 + quad * 8);
                    acc[j] = mfma_bf16(qf[ks], kf, acc[j]);
                }
            }
            __builtin_amdgcn_s_setprio(0);

            // P tile to zero so PV's nt range [2p, 2p+9] reads only written/zeroed data
            const int ntz = qq ? (qtile - 1) : (qtile + 9);

            float linv[4];
#pragma unroll
            for (int r = 0; r < 4; ++r) {
                const int ql = qtile * 16 + quad * 4 + r;
                float e[9];
                float mx = -1e30f;
#pragma unroll
                for (int j = 0; j < 9; ++j) {
                    int row_k = (qtile + j) * 16 + l16;
                    bool valid = (row_k >= ql) && (row_k <= ql + 127) && (w0 + row_k >= 0);
                    float s = valid ? acc[j][r] * SM_SCALE : -1e30f;
                    e[j] = s;
                    mx = fmaxf(mx, s);
                }
#pragma unroll
                for (int o = 1; o < 16; o <<= 1) mx = fmaxf(mx, __shfl_xor(mx, o));
                float M = fmaxf(mx, sink_f);
                float ls = 0.f;
#pragma unroll
                for (int j = 0; j < 9; ++j) {
                    float ev = (e[j] > -1e29f) ? __expf(e[j] - M) : 0.f;
                    e[j] = ev;
                    ls += ev;
                }
#pragma unroll
                for (int o = 1; o < 16; o <<= 1) ls += __shfl_xor(ls, o);
                linv[r] = 1.f / (ls + __expf(sink_f - M));
#pragma unroll
                for (int j = 0; j < 9; ++j)
                    Pw[(quad * 4 + r) * LDP + (qtile + j) * 16 + l16] = f2bf(e[j]);
                Pw[(quad * 4 + r) * LDP + ntz * 16 + l16] = 0;
            }

            // PV over the 5 valid k-slices (kt = p + j, matching Vf[j])
            float4v accO[4];
#pragma unroll
            for (int nv = 0; nv < 4; ++nv) accO[nv] = (float4v){0.f, 0.f, 0.f, 0.f};
            __builtin_amdgcn_s_setprio(1);
#pragma unroll
            for (int j = 0; j < 5; ++j) {
                short8 pf = *(const short8*)(Pw + l16 * LDP + (p + j) * 32 + quad * 8);
#pragma unroll
                for (int nv = 0; nv < 4; ++nv) accO[nv] = mfma_bf16(pf, Vf[j][nv], accO[nv]);
            }
            __builtin_amdgcn_s_setprio(0);

#pragma unroll
            for (int r = 0; r < 4; ++r) {
                size_t ob = ((size_t)(tokb + quad * 4 + r)) * ATTN_DIM + h * 64 + l16;
#pragma unroll
                for (int nv = 0; nv < 4; ++nv)
                    attnbuf[ob + nv * 16] = f2bf(accO[nv][r] * linv[r]);
            }
        }
    }
}

// ---------- launch ----------
extern "C" void kernel_launch(void* const* d_in, const int* in_sizes, int n_in,
                              void* d_out, int out_size, void* d_ws, size_t ws_size,
                              hipStream_t stream) {
    const float* x = (const float*)d_in[0];
    const float* norm_w = (const float*)d_in[1];
    const float* qkv_w = (const float*)d_in[2];
    const float* qkv_b = (const float*)d_in[3];
    const float* out_w = (const float*)d_in[4];
    const float* out_b = (const float*)d_in[5];
    const float* sinks = (const float*)d_in[6];
    float* outp = (float*)d_out;
    char* ws = (char*)d_ws;

    if (ws_size >= 86000000ull) {
        // ws: qkvbuf 21MB | {qkv_w_bf 29.5MB -> attnbuf 16.8MB} | out_w_bf 23.6MB
        // Tbuf lives in d_out (dead before GEMM2 overwrites d_out).
        ushort_t* qkvbuf = (ushort_t*)ws;
        ushort_t* qkv_w_bf = (ushort_t*)(ws + 20971520);
        ushort_t* attnbuf = (ushort_t*)(ws + 20971520);  // reuse after gemm1 consumed qkv_w_bf
        ushort_t* out_w_bf = (ushort_t*)(ws + 50462720);
        ushort_t* Tbuf = (ushort_t*)d_out;

        // prep: 2048 rmsnorm blocks + 12960 conversion blocks in one launch
        prep_kernel<<<NTOK + 12960, 256, 0, stream>>>(x, norm_w, Tbuf, qkv_w, qkv_w_bf,
                                                      1843200, out_w, out_w_bf, 1474560);
        gemm_kernel<160, false, false, true><<<dim3(32, 16), 256, 0, stream>>>(
            Tbuf, qkv_w_bf, qkv_b, nullptr, qkvbuf, NTOK, QKV_DIM, HIDDEN);
        attn_mfma_kernel<<<dim3(16, 16, 2), 256, 0, stream>>>(qkvbuf, sinks, attnbuf);
        // GEMM2: B direct-to-registers (BREG) - K=4096 -> nk=64 even as required
        gemm_kernel<96, true, true, true, true><<<dim3(30, 16), 256, 0, stream>>>(
            attnbuf, out_w_bf, out_b, x, outp, NTOK, HIDDEN, ATTN_DIM);
    } else {
        // fallback: fp32 B loads (register staging), Tbuf in d_out
        ushort_t* qkvbuf = (ushort_t*)ws;
        ushort_t* attnbuf = (ushort_t*)(ws + 20971520);
        ushort_t* Tbuf = (ushort_t*)d_out;

        rmsnorm_kernel<<<NTOK, 256, 0, stream>>>(x, norm_w, Tbuf);
        gemm_kernel<128, false, false, false><<<dim3(40, 16), 256, 0, stream>>>(
            Tbuf, qkv_w, qkv_b, nullptr, qkvbuf, NTOK, QKV_DIM, HIDDEN);
        attn_mfma_kernel<<<dim3(16, 16, 2), 256, 0, stream>>>(qkvbuf, sinks, attnbuf);
        gemm_kernel<96, true, true, false><<<dim3(30, 16), 256, 0, stream>>>(
            attnbuf, out_w, out_b, x, outp, NTOK, HIDDEN, ATTN_DIM);
    }
}

// Round 9
// 314.074 us; speedup vs baseline: 1.1568x; 1.1568x over previous
//
#include <hip/hip_runtime.h>

typedef unsigned short ushort_t;
typedef __attribute__((ext_vector_type(8))) short short8;
typedef __attribute__((ext_vector_type(8))) __bf16 bf16x8;
typedef __attribute__((ext_vector_type(4))) float float4v;
typedef __attribute__((ext_vector_type(4))) unsigned int uint4v;

// ---------- bf16 helpers ----------
__device__ __forceinline__ float bf2f(ushort_t u) {
    unsigned int v = ((unsigned int)u) << 16;
    return __builtin_bit_cast(float, v);
}
__device__ __forceinline__ ushort_t f2bf(float f) {
    unsigned int u = __builtin_bit_cast(unsigned int, f);
    unsigned int lsb = (u >> 16) & 1u;
    u += 0x7fffu + lsb;  // round-to-nearest-even
    return (ushort_t)(u >> 16);
}
__device__ __forceinline__ uint4v pack8(const ushort_t* r) {
    uint4v u;
#pragma unroll
    for (int i = 0; i < 4; ++i)
        u[i] = (unsigned int)r[2 * i] | ((unsigned int)r[2 * i + 1] << 16);
    return u;
}
__device__ __forceinline__ void unpack8(uint4v u, float* f) {
#pragma unroll
    for (int i = 0; i < 4; ++i) {
        unsigned int x = u[i];
        f[2 * i] = __builtin_bit_cast(float, x << 16);
        f[2 * i + 1] = __builtin_bit_cast(float, x & 0xffff0000u);
    }
}
__device__ __forceinline__ uint4v ld8f32_bf(const float* p) {
    float4v a = *(const float4v*)p;
    float4v b = *(const float4v*)(p + 4);
    ushort_t r[8];
#pragma unroll
    for (int j = 0; j < 4; ++j) { r[j] = f2bf(a[j]); r[4 + j] = f2bf(b[j]); }
    return pack8(r);
}

// ---------- async global->LDS (16B per lane, dest = uniform base + lane*16) ----------
#if __has_builtin(__builtin_amdgcn_global_load_lds)
#define HAVE_GLDS 1
__device__ __forceinline__ void glds16(const ushort_t* gp, ushort_t* lp) {
    __builtin_amdgcn_global_load_lds((const __attribute__((address_space(1))) void*)gp,
                                     (__attribute__((address_space(3))) void*)lp, 16, 0, 0);
}
#else
#define HAVE_GLDS 0
#endif

// ---------- MFMA hedge ----------
template <typename V>
__device__ __forceinline__ auto mfma_sel(V a, V b, float4v c, int)
    -> decltype(__builtin_amdgcn_mfma_f32_16x16x32_bf16(a, b, c, 0, 0, 0)) {
    return __builtin_amdgcn_mfma_f32_16x16x32_bf16(a, b, c, 0, 0, 0);
}
template <typename V>
__device__ __forceinline__ float4v mfma_sel(V a, V b, float4v c, long) {
    return __builtin_amdgcn_mfma_f32_16x16x32_bf16(__builtin_bit_cast(bf16x8, a),
                                                   __builtin_bit_cast(bf16x8, b), c, 0, 0, 0);
}
__device__ __forceinline__ float4v mfma_bf16(short8 a, short8 b, float4v c) {
    return mfma_sel(a, b, c, 0);
}

__device__ __forceinline__ float wave_sum(float v) {
#pragma unroll
    for (int o = 32; o; o >>= 1) v += __shfl_xor(v, o);
    return v;
}

// ---------- constants ----------
#define HIDDEN 2880
#define NTOK 2048
#define QKV_DIM 5120
#define ATTN_DIM 4096
#define SM_SCALE 0.125f

// YaRN rope constants (shared by attn fused rope)
#define ROPE_STEP 0.37244970540869975f   /* 11.918390573078392 / 32 */
#define ROPE_CONC 1.3465735902799727f
#define ROPE_LOW 8.092890725542669f
#define ROPE_INVDEN 0.10745959154836568f /* 1 / 9.305804387286162 */

__device__ __forceinline__ float rope_invfreq(int j) {
    float invf = __expf(-(float)j * ROPE_STEP);
    float ramp = ((float)j - ROPE_LOW) * ROPE_INVDEN;
    float mask = 1.f - fminf(fmaxf(ramp, 0.f), 1.f);
    return invf * ((1.f - mask) * 0.03125f + mask);
}

// ---------- prep: rmsnorm (blocks 0..2047) + qkv_w fp32->bf16 convert (rest) ----------
// out_w conversion moved into the attn kernel (r9): in prep it contends with rmsnorm
// for HBM; under attn (MFMA/latency-bound, HBM idle) it overlaps for free.
__global__ __launch_bounds__(256) void prep_kernel(const float* __restrict__ x,
                                                   const float* __restrict__ wgt,
                                                   ushort_t* __restrict__ tout,
                                                   const float* __restrict__ a,
                                                   ushort_t* __restrict__ ao, int na8) {
    const int tid = threadIdx.x;
    __shared__ float red[4];
    if (blockIdx.x < NTOK) {
        // ---- RMSNorm for token blockIdx.x ----
        const int tok = blockIdx.x;
        const float* xr = x + (size_t)tok * HIDDEN;
        float v[16];
        float ss = 0.f;
#pragma unroll
        for (int i = 0; i < 2; ++i) {
            int c = tid + i * 256;
            if (c < 360) {
                float4v va = *(const float4v*)(xr + c * 8);
                float4v vb = *(const float4v*)(xr + c * 8 + 4);
#pragma unroll
                for (int j = 0; j < 4; ++j) { v[i * 8 + j] = va[j]; v[i * 8 + 4 + j] = vb[j]; }
#pragma unroll
                for (int j = 0; j < 8; ++j) ss += v[i * 8 + j] * v[i * 8 + j];
            }
        }
        ss = wave_sum(ss);
        if ((tid & 63) == 0) red[tid >> 6] = ss;
        __syncthreads();
        float scale = rsqrtf((red[0] + red[1] + red[2] + red[3]) * (1.f / 2880.f) + 1e-5f);
#pragma unroll
        for (int i = 0; i < 2; ++i) {
            int c = tid + i * 256;
            if (c < 360) {
                float4v wa = *(const float4v*)(wgt + c * 8);
                float4v wb = *(const float4v*)(wgt + c * 8 + 4);
                ushort_t r[8];
#pragma unroll
                for (int j = 0; j < 4; ++j) {
                    r[j] = f2bf(v[i * 8 + j] * scale * wa[j]);
                    r[4 + j] = f2bf(v[i * 8 + 4 + j] * scale * wb[j]);
                }
                *(uint4v*)(tout + (size_t)tok * HIDDEN + c * 8) = pack8(r);
            }
        }
    } else {
        // ---- qkv_w conversion (needed by gemm1, so it stays in prep) ----
        int idx = (blockIdx.x - NTOK) * 256 + tid;
        if (idx < na8) *(uint4v*)(ao + (size_t)idx * 8) = ld8f32_bf(a + (size_t)idx * 8);
    }
}

// ---------- RMSNorm standalone (fallback path) ----------
__global__ __launch_bounds__(256) void rmsnorm_kernel(const float* __restrict__ x,
                                                      const float* __restrict__ wgt,
                                                      ushort_t* __restrict__ out) {
    const int tok = blockIdx.x, tid = threadIdx.x;
    const float* xr = x + (size_t)tok * HIDDEN;
    float v[16];
    float ss = 0.f;
#pragma unroll
    for (int i = 0; i < 2; ++i) {
        int c = tid + i * 256;
        if (c < 360) {
            float4v a = *(const float4v*)(xr + c * 8);
            float4v b = *(const float4v*)(xr + c * 8 + 4);
#pragma unroll
            for (int j = 0; j < 4; ++j) { v[i * 8 + j] = a[j]; v[i * 8 + 4 + j] = b[j]; }
#pragma unroll
            for (int j = 0; j < 8; ++j) ss += v[i * 8 + j] * v[i * 8 + j];
        }
    }
    ss = wave_sum(ss);
    __shared__ float red[4];
    if ((tid & 63) == 0) red[tid >> 6] = ss;
    __syncthreads();
    float scale = rsqrtf((red[0] + red[1] + red[2] + red[3]) * (1.f / 2880.f) + 1e-5f);
#pragma unroll
    for (int i = 0; i < 2; ++i) {
        int c = tid + i * 256;
        if (c < 360) {
            float4v wa = *(const float4v*)(wgt + c * 8);
            float4v wb = *(const float4v*)(wgt + c * 8 + 4);
            ushort_t r[8];
#pragma unroll
            for (int j = 0; j < 4; ++j) {
                r[j] = f2bf(v[i * 8 + j] * scale * wa[j]);
                r[4 + j] = f2bf(v[i * 8 + 4 + j] * scale * wb[j]);
            }
            *(uint4v*)(out + (size_t)tok * HIDDEN + c * 8) = pack8(r);
        }
    }
}

// ---------- GEMM: C[M,N] = A[M,K](bf16) @ B[N,K]^T + bias (+ resid) ----------
// FROZEN (r8): the 2-phase glds + single-barrier template is a measured local
//   optimum at this geometry. Perturbations all regressed:
//   - counted-vmcnt 2-barrier pipeline (r2): -17%
//   - BN=128 padded-N for better amortization (r3): -11% (residency quantization)
//   - BREG B-direct-to-registers (r8): -2x (116us, MfmaUtil 16%, VALUBusy 7.5%)
//   glds DMA for BOTH operands is strictly best here; do not reintroduce variants.
// Blocks: flattened id XCD-swizzled (T1, bijective since nwg%8==0 for all grids).
// Grid-residency (r3): at 2 blocks/CU capacity, prefer grids just under 512.
template <int BN, bool RESID, bool OUTF32, bool BF16B>
__global__ __launch_bounds__(256) void gemm_kernel(const ushort_t* __restrict__ A,
                                                   const void* __restrict__ B,
                                                   const float* __restrict__ bias,
                                                   const float* __restrict__ resid,
                                                   void* __restrict__ Cout, int M, int N, int K) {
    constexpr int BM = 128, BK = 64;
    constexpr bool GL = BF16B && (HAVE_GLDS != 0);
    constexpr int LDT = GL ? 64 : 72;
    constexpr int NBUF = GL ? 2 : 1;
    static_assert(BN == 160 || BN == 128 || BN == 96 || BN == 64, "");
    __shared__ __align__(16) ushort_t As[NBUF][BM * LDT];
    __shared__ __align__(16) ushort_t Bs[NBUF][BN * LDT];

    // XCD-aware chunked swizzle of the flattened block id (nwg % 8 == 0 for all grids)
    const int nbx = gridDim.x;
    int wg = blockIdx.y * nbx + blockIdx.x;
    {
        const int nwg = nbx * gridDim.y;
        const int cpx = nwg >> 3;
        wg = (wg & 7) * cpx + (wg >> 3);
    }
    const int m0 = (wg / nbx) * BM;
    const int n0 = (wg % nbx) * BN;
    const int tid = threadIdx.x;
    const int w = tid >> 6, lane = tid & 63;
    const int quad = lane >> 4, l16 = lane & 15;

    constexpr int WN = BN / 2;
    constexpr int NI = WN / 16;  // 5 / 4 / 3 / 2
    const int wm = (w >> 1) * 64;
    const int wn = (w & 1) * WN;

    float4v acc[4][NI];
#pragma unroll
    for (int i = 0; i < 4; ++i)
#pragma unroll
        for (int j = 0; j < NI; ++j) acc[i][j] = (float4v){0.f, 0.f, 0.f, 0.f};

    const int nk = K / BK;

#if HAVE_GLDS
    if constexpr (GL) {
        constexpr int NAI = BM / 32;  // glds issues per wave for A
        constexpr int NBI = BN / 32;  // glds issues per wave for B
        const ushort_t* Bp = (const ushort_t*)B;
        const ushort_t* agp[NAI];
        const ushort_t* bgp[NBI];
        ushort_t* alp[2][NAI];
        ushort_t* blp[2][NBI];
#pragma unroll
        for (int i = 0; i < NAI; ++i) {
            int sb = (w * NAI + i) * 64;
            int s = sb + lane, r = s >> 3, p = s & 7, c = p ^ (r & 7);
            agp[i] = A + (size_t)(m0 + r) * K + c * 8;
            alp[0][i] = &As[0][sb * 8];
            alp[1][i] = &As[1][sb * 8];
        }
#pragma unroll
        for (int i = 0; i < NBI; ++i) {
            int sb = (w * NBI + i) * 64;
            int s = sb + lane, r = s >> 3, p = s & 7, c = p ^ (r & 7);
            bgp[i] = Bp + (size_t)(n0 + r) * K + c * 8;
            blp[0][i] = &Bs[0][sb * 8];
            blp[1][i] = &Bs[1][sb * 8];
        }
        // prologue: tile 0 -> buf 0
#pragma unroll
        for (int i = 0; i < NAI; ++i) glds16(agp[i], alp[0][i]);
#pragma unroll
        for (int i = 0; i < NBI; ++i) glds16(bgp[i], blp[0][i]);
        __syncthreads();

        for (int kt = 0; kt < nk; ++kt) {
            const int cur = kt & 1;
            if (kt + 1 < nk) {
                const int k0 = (kt + 1) * BK;
#pragma unroll
                for (int i = 0; i < NAI; ++i) glds16(agp[i] + k0, alp[cur ^ 1][i]);
#pragma unroll
                for (int i = 0; i < NBI; ++i) glds16(bgp[i] + k0, blp[cur ^ 1][i]);
            }
            const ushort_t* Asb = As[cur];
            const ushort_t* Bsb = Bs[cur];
#pragma unroll
            for (int ks = 0; ks < 2; ++ks) {
                short8 af[4], bfr[NI];
#pragma unroll
                for (int mi = 0; mi < 4; ++mi) {
                    int row = wm + mi * 16 + l16;
                    af[mi] = *(const short8*)(Asb + row * LDT + ((ks * 4 + quad) ^ (row & 7)) * 8);
                }
#pragma unroll
                for (int ni = 0; ni < NI; ++ni) {
                    int row = wn + ni * 16 + l16;
                    bfr[ni] = *(const short8*)(Bsb + row * LDT + ((ks * 4 + quad) ^ (row & 7)) * 8);
                }
#pragma unroll
                for (int mi = 0; mi < 4; ++mi)
#pragma unroll
                    for (int ni = 0; ni < NI; ++ni)
                        acc[mi][ni] = mfma_bf16(af[mi], bfr[ni], acc[mi][ni]);
            }
            __syncthreads();
        }
    } else
#endif
    {
        // fallback: padded LDS + register prefetch (round-5 structure)
        constexpr int ACH = BM * BK / 8 / 256;
        constexpr int BCH = BN * BK / 8 / 256;
        uint4v areg[ACH], breg[BCH];
#pragma unroll
        for (int i = 0; i < ACH; ++i) {
            int c = tid + i * 256, r = c >> 3, col = c & 7;
            areg[i] = *(const uint4v*)(A + (size_t)(m0 + r) * K + col * 8);
        }
#pragma unroll
        for (int i = 0; i < BCH; ++i) {
            int c = tid + i * 256, r = c >> 3, col = c & 7;
            if constexpr (BF16B)
                breg[i] = *(const uint4v*)((const ushort_t*)B + (size_t)(n0 + r) * K + col * 8);
            else
                breg[i] = ld8f32_bf((const float*)B + (size_t)(n0 + r) * K + col * 8);
        }
        for (int kt = 0; kt < nk; ++kt) {
            __syncthreads();
#pragma unroll
            for (int i = 0; i < ACH; ++i) {
                int c = tid + i * 256, r = c >> 3, col = c & 7;
                *(uint4v*)(&As[0][r * LDT + col * 8]) = areg[i];
            }
#pragma unroll
            for (int i = 0; i < BCH; ++i) {
                int c = tid + i * 256, r = c >> 3, col = c & 7;
                *(uint4v*)(&Bs[0][(size_t)r * LDT + col * 8]) = breg[i];
            }
            __syncthreads();
            if (kt + 1 < nk) {
                const int k0 = (kt + 1) * BK;
#pragma unroll
                for (int i = 0; i < ACH; ++i) {
                    int c = tid + i * 256, r = c >> 3, col = c & 7;
                    areg[i] = *(const uint4v*)(A + (size_t)(m0 + r) * K + k0 + col * 8);
                }
#pragma unroll
                for (int i = 0; i < BCH; ++i) {
                    int c = tid + i * 256, r = c >> 3, col = c & 7;
                    if constexpr (BF16B)
                        breg[i] = *(const uint4v*)((const ushort_t*)B + (size_t)(n0 + r) * K + k0 + col * 8);
                    else
                        breg[i] = ld8f32_bf((const float*)B + (size_t)(n0 + r) * K + k0 + col * 8);
                }
            }
#pragma unroll
            for (int ks = 0; ks < 2; ++ks) {
                short8 af[4], bfr[NI];
#pragma unroll
                for (int mi = 0; mi < 4; ++mi)
                    af[mi] = *(const short8*)(&As[0][(wm + mi * 16 + l16) * LDT + ks * 32 + quad * 8]);
#pragma unroll
                for (int ni = 0; ni < NI; ++ni)
                    bfr[ni] = *(const short8*)(&Bs[0][(size_t)(wn + ni * 16 + l16) * LDT + ks * 32 + quad * 8]);
#pragma unroll
                for (int mi = 0; mi < 4; ++mi)
#pragma unroll
                    for (int ni = 0; ni < NI; ++ni)
                        acc[mi][ni] = mfma_bf16(af[mi], bfr[ni], acc[mi][ni]);
            }
        }
    }

    // epilogue: C/D layout col = lane&15, row = quad*4 + reg
#pragma unroll
    for (int ni = 0; ni < NI; ++ni) {
        int gc = n0 + wn + ni * 16 + l16;
        float bv = bias[gc];
#pragma unroll
        for (int mi = 0; mi < 4; ++mi) {
#pragma unroll
            for (int r = 0; r < 4; ++r) {
                int gr = m0 + wm + mi * 16 + quad * 4 + r;
                float vv = acc[mi][ni][r] + bv;
                if constexpr (RESID) vv += resid[(size_t)gr * N + gc];
                if constexpr (OUTF32) ((float*)Cout)[(size_t)gr * N + gc] = vv;
                else ((ushort_t*)Cout)[(size_t)gr * N + gc] = f2bf(vv);
            }
        }
    }
}

// ---------- MFMA attention: sliding window 128 + sink, RoPE fused on load ----------
// Grid (16+CONVX, 16, 2): blockIdx.x < 16 -> attention (qc = blockIdx.x);
//   blockIdx.x >= 16 -> out_w fp32->bf16 conversion backfill (r9): attn is
//   MFMA/latency-bound with idle HBM, so the conversion's ~71MB of traffic
//   overlaps under attn compute instead of contending with rmsnorm in prep.
//   1440 conv blocks x 256 thr x 4 chunks = 1474560 chunks exactly.
// Attention: wave w handles head kvh*8 + half*4 + w, 4 query-tiles of 16.
// RoPE fusion (r6): qkvbuf is UN-roped; q/k regions are consumed only here.
// Window-aware compute: q-tile qtile touches key-tiles qtile..qtile+8 and PV slices
//   kt = (qtile>>1)..+4. Pair structure: q-tiles (2p,2p+1) share Vf[5][4] hoist.
#define CONVX 45
__global__ __launch_bounds__(256, 2) void attn_mfma_kernel(const ushort_t* __restrict__ qkv,
                                                           const float* __restrict__ sinks,
                                                           ushort_t* __restrict__ attnbuf,
                                                           const float* __restrict__ ow,
                                                           ushort_t* __restrict__ ow_bf) {
    constexpr int LDK = 72, LDV = 200, LDP = 200;
    __shared__ __align__(16) ushort_t Ks[192 * LDK];
    __shared__ __align__(16) ushort_t Vt[64 * LDV];
    __shared__ __align__(16) ushort_t Pb[4][16 * LDP];

    if (blockIdx.x >= 16) {
        // ---- out_w conversion backfill (uniform block-level branch) ----
        const int conv_id = (blockIdx.x - 16) + CONVX * (blockIdx.y * 2 + blockIdx.z);
        const int base = conv_id * 256 + threadIdx.x;
#pragma unroll
        for (int k = 0; k < 4; ++k) {
            int idx = base + k * (CONVX * 32 * 256);  // stride 368640
            *(uint4v*)(ow_bf + (size_t)idx * 8) = ld8f32_bf(ow + (size_t)idx * 8);
        }
        return;
    }

    const int qc = blockIdx.x, kvh = blockIdx.y >> 1, half = blockIdx.y & 1, b = blockIdx.z;
    const int tid = threadIdx.x;
    const int w = tid >> 6, lane = tid & 63;
    const int quad = lane >> 4, l16 = lane & 15;
    const int w0 = qc * 64 - 127;  // key position of LDS row 0

    // K stage + rope: 3 iters; lane owns dims [col4*8,+8) and [+32,+8) of row c>>2.
    {
        float invfK[8];
#pragma unroll
        for (int jj = 0; jj < 8; ++jj) invfK[jj] = rope_invfreq((tid & 3) * 8 + jj);
        for (int c = tid; c < 192 * 4; c += 256) {
            int row = c >> 2, col4 = c & 3;
            int pos = w0 + row;
            pos = pos < 0 ? 0 : (pos > 1023 ? 1023 : pos);
            size_t gk = ((size_t)(b * 1024 + pos)) * QKV_DIM + 4096 + kvh * 64 + col4 * 8;
            uint4v u1 = *(const uint4v*)(qkv + gk);
            uint4v u2 = *(const uint4v*)(qkv + gk + 32);
            float f1[8], f2[8];
            unpack8(u1, f1);
            unpack8(u2, f2);
            float s = (float)pos;
            ushort_t r1[8], r2[8];
#pragma unroll
            for (int jj = 0; jj < 8; ++jj) {
                float ang = s * invfK[jj];
                float cc = __cosf(ang) * ROPE_CONC;
                float sn = __sinf(ang) * ROPE_CONC;
                r1[jj] = f2bf(f1[jj] * cc - f2[jj] * sn);
                r2[jj] = f2bf(f2[jj] * cc + f1[jj] * sn);
            }
            *(uint4v*)(Ks + row * LDK + col4 * 8) = pack8(r1);
            *(uint4v*)(Ks + row * LDK + (col4 + 4) * 8) = pack8(r2);
        }
    }
    // V stage (transpose), no rope
    for (int c = tid; c < 192 * 8; c += 256) {
        int row = c >> 3, col8 = c & 7;
        int pos = w0 + row;
        pos = pos < 0 ? 0 : (pos > 1023 ? 1023 : pos);
        size_t gv = ((size_t)(b * 1024 + pos)) * QKV_DIM + 4608 + kvh * 64 + col8 * 8;
        uint4v vv = *(const uint4v*)(qkv + gv);
        ushort_t vs[8];
#pragma unroll
        for (int i = 0; i < 4; ++i) {
            vs[2 * i] = (ushort_t)(vv[i] & 0xffffu);
            vs[2 * i + 1] = (ushort_t)(vv[i] >> 16);
        }
#pragma unroll
        for (int j = 0; j < 8; ++j) Vt[(col8 * 8 + j) * LDV + row] = vs[j];
    }
    __syncthreads();

    ushort_t* Pw = Pb[w];
    const int h = kvh * 8 + half * 4 + w;
    const float sink_f = sinks[h];

    // per-lane Q rope inv_freq: j = quad*8+jj
    float invfQ[8];
#pragma unroll
    for (int jj = 0; jj < 8; ++jj) invfQ[jj] = rope_invfreq(quad * 8 + jj);

    for (int p = 0; p < 2; ++p) {  // q-tile pair: q-tiles 2p, 2p+1 share PV kt = p..p+4
        short8 Vf[5][4];
#pragma unroll
        for (int j = 0; j < 5; ++j)
#pragma unroll
            for (int nv = 0; nv < 4; ++nv)
                Vf[j][nv] = *(const short8*)(Vt + (nv * 16 + l16) * LDV + (p + j) * 32 + quad * 8);

#pragma unroll
        for (int qq = 0; qq < 2; ++qq) {
            const int qtile = 2 * p + qq;
            const int tokb = b * 1024 + qc * 64 + qtile * 16;

            // Q load + lane-local rope
            short8 qf[2];
            {
                const ushort_t* qp = qkv + ((size_t)(tokb + l16)) * QKV_DIM + h * 64 + quad * 8;
                uint4v u1 = *(const uint4v*)qp;
                uint4v u2 = *(const uint4v*)(qp + 32);
                float f1[8], f2[8];
                unpack8(u1, f1);
                unpack8(u2, f2);
                float s = (float)((tokb + l16) & 1023);
                ushort_t r1[8], r2[8];
#pragma unroll
                for (int jj = 0; jj < 8; ++jj) {
                    float ang = s * invfQ[jj];
                    float cc = __cosf(ang) * ROPE_CONC;
                    float sn = __sinf(ang) * ROPE_CONC;
                    r1[jj] = f2bf(f1[jj] * cc - f2[jj] * sn);
                    r2[jj] = f2bf(f2[jj] * cc + f1[jj] * sn);
                }
                qf[0] = __builtin_bit_cast(short8, pack8(r1));
                qf[1] = __builtin_bit_cast(short8, pack8(r2));
            }

            // QK^T over the 9 valid key-tiles (nt = qtile + j)
            float4v acc[9];
#pragma unroll
            for (int j = 0; j < 9; ++j) acc[j] = (float4v){0.f, 0.f, 0.f, 0.f};
            __builtin_amdgcn_s_setprio(1);
#pragma unroll
            for (int j = 0; j < 9; ++j) {
                const int nt = qtile + j;
#pragma unroll
                for (int ks = 0; ks < 2; ++ks) {
                    short8 kf = *(const short8*)(Ks + (nt * 16 + l16) * LDK + ks * 32 + quad * 8);
                    acc[j] = mfma_bf16(qf[ks], kf, acc[j]);
                }
            }
            __builtin_amdgcn_s_setprio(0);

            // P tile to zero so PV's nt range [2p, 2p+9] reads only written/zeroed data
            const int ntz = qq ? (qtile - 1) : (qtile + 9);

            float linv[4];
#pragma unroll
            for (int r = 0; r < 4; ++r) {
                const int ql = qtile * 16 + quad * 4 + r;
                float e[9];
                float mx = -1e30f;
#pragma unroll
                for (int j = 0; j < 9; ++j) {
                    int row_k = (qtile + j) * 16 + l16;
                    bool valid = (row_k >= ql) && (row_k <= ql + 127) && (w0 + row_k >= 0);
                    float s = valid ? acc[j][r] * SM_SCALE : -1e30f;
                    e[j] = s;
                    mx = fmaxf(mx, s);
                }
#pragma unroll
                for (int o = 1; o < 16; o <<= 1) mx = fmaxf(mx, __shfl_xor(mx, o));
                float M = fmaxf(mx, sink_f);
                float ls = 0.f;
#pragma unroll
                for (int j = 0; j < 9; ++j) {
                    float ev = (e[j] > -1e29f) ? __expf(e[j] - M) : 0.f;
                    e[j] = ev;
                    ls += ev;
                }
#pragma unroll
                for (int o = 1; o < 16; o <<= 1) ls += __shfl_xor(ls, o);
                linv[r] = 1.f / (ls + __expf(sink_f - M));
#pragma unroll
                for (int j = 0; j < 9; ++j)
                    Pw[(quad * 4 + r) * LDP + (qtile + j) * 16 + l16] = f2bf(e[j]);
                Pw[(quad * 4 + r) * LDP + ntz * 16 + l16] = 0;
            }

            // PV over the 5 valid k-slices (kt = p + j, matching Vf[j])
            float4v accO[4];
#pragma unroll
            for (int nv = 0; nv < 4; ++nv) accO[nv] = (float4v){0.f, 0.f, 0.f, 0.f};
            __builtin_amdgcn_s_setprio(1);
#pragma unroll
            for (int j = 0; j < 5; ++j) {
                short8 pf = *(const short8*)(Pw + l16 * LDP + (p + j) * 32 + quad * 8);
#pragma unroll
                for (int nv = 0; nv < 4; ++nv) accO[nv] = mfma_bf16(pf, Vf[j][nv], accO[nv]);
            }
            __builtin_amdgcn_s_setprio(0);

#pragma unroll
            for (int r = 0; r < 4; ++r) {
                size_t ob = ((size_t)(tokb + quad * 4 + r)) * ATTN_DIM + h * 64 + l16;
#pragma unroll
                for (int nv = 0; nv < 4; ++nv)
                    attnbuf[ob + nv * 16] = f2bf(accO[nv][r] * linv[r]);
            }
        }
    }
}

// ---------- launch ----------
extern "C" void kernel_launch(void* const* d_in, const int* in_sizes, int n_in,
                              void* d_out, int out_size, void* d_ws, size_t ws_size,
                              hipStream_t stream) {
    const float* x = (const float*)d_in[0];
    const float* norm_w = (const float*)d_in[1];
    const float* qkv_w = (const float*)d_in[2];
    const float* qkv_b = (const float*)d_in[3];
    const float* out_w = (const float*)d_in[4];
    const float* out_b = (const float*)d_in[5];
    const float* sinks = (const float*)d_in[6];
    float* outp = (float*)d_out;
    char* ws = (char*)d_ws;

    if (ws_size >= 86000000ull) {
        // ws: qkvbuf 21MB | {qkv_w_bf 29.5MB -> attnbuf 16.8MB} | out_w_bf 23.6MB
        // Tbuf lives in d_out (dead before GEMM2 overwrites d_out).
        ushort_t* qkvbuf = (ushort_t*)ws;
        ushort_t* qkv_w_bf = (ushort_t*)(ws + 20971520);
        ushort_t* attnbuf = (ushort_t*)(ws + 20971520);  // reuse after gemm1 consumed qkv_w_bf
        ushort_t* out_w_bf = (ushort_t*)(ws + 50462720);
        ushort_t* Tbuf = (ushort_t*)d_out;

        // prep: 2048 rmsnorm blocks + 7200 qkv_w-conversion blocks
        prep_kernel<<<NTOK + 7200, 256, 0, stream>>>(x, norm_w, Tbuf, qkv_w, qkv_w_bf,
                                                     1843200);
        gemm_kernel<160, false, false, true><<<dim3(32, 16), 256, 0, stream>>>(
            Tbuf, qkv_w_bf, qkv_b, nullptr, qkvbuf, NTOK, QKV_DIM, HIDDEN);
        // attn (512 blocks) + out_w conversion backfill (1440 blocks)
        attn_mfma_kernel<<<dim3(16 + CONVX, 16, 2), 256, 0, stream>>>(
            qkvbuf, sinks, attnbuf, out_w, out_w_bf);
        gemm_kernel<96, true, true, true><<<dim3(30, 16), 256, 0, stream>>>(
            attnbuf, out_w_bf, out_b, x, outp, NTOK, HIDDEN, ATTN_DIM);
    } else {
        // fallback: fp32 B loads (register staging), Tbuf in d_out
        ushort_t* qkvbuf = (ushort_t*)ws;
        ushort_t* attnbuf = (ushort_t*)(ws + 20971520);
        ushort_t* Tbuf = (ushort_t*)d_out;

        rmsnorm_kernel<<<NTOK, 256, 0, stream>>>(x, norm_w, Tbuf);
        gemm_kernel<128, false, false, false><<<dim3(40, 16), 256, 0, stream>>>(
            Tbuf, qkv_w, qkv_b, nullptr, qkvbuf, NTOK, QKV_DIM, HIDDEN);
        attn_mfma_kernel<<<dim3(16, 16, 2), 256, 0, stream>>>(
            qkvbuf, sinks, attnbuf, nullptr, nullptr);
        gemm_kernel<96, true, true, false><<<dim3(30, 16), 256, 0, stream>>>(
            attnbuf, out_w, out_b, x, outp, NTOK, HIDDEN, ATTN_DIM);
    }
}

// Round 10
// 310.103 us; speedup vs baseline: 1.1717x; 1.0128x over previous
//
#include <hip/hip_runtime.h>

typedef unsigned short ushort_t;
typedef __attribute__((ext_vector_type(8))) short short8;
typedef __attribute__((ext_vector_type(8))) __bf16 bf16x8;
typedef __attribute__((ext_vector_type(4))) float float4v;
typedef __attribute__((ext_vector_type(4))) unsigned int uint4v;

// ---------- bf16 helpers ----------
__device__ __forceinline__ float bf2f(ushort_t u) {
    unsigned int v = ((unsigned int)u) << 16;
    return __builtin_bit_cast(float, v);
}
__device__ __forceinline__ ushort_t f2bf(float f) {
    unsigned int u = __builtin_bit_cast(unsigned int, f);
    unsigned int lsb = (u >> 16) & 1u;
    u += 0x7fffu + lsb;  // round-to-nearest-even
    return (ushort_t)(u >> 16);
}
__device__ __forceinline__ uint4v pack8(const ushort_t* r) {
    uint4v u;
#pragma unroll
    for (int i = 0; i < 4; ++i)
        u[i] = (unsigned int)r[2 * i] | ((unsigned int)r[2 * i + 1] << 16);
    return u;
}
__device__ __forceinline__ void unpack8(uint4v u, float* f) {
#pragma unroll
    for (int i = 0; i < 4; ++i) {
        unsigned int x = u[i];
        f[2 * i] = __builtin_bit_cast(float, x << 16);
        f[2 * i + 1] = __builtin_bit_cast(float, x & 0xffff0000u);
    }
}
__device__ __forceinline__ uint4v ld8f32_bf(const float* p) {
    float4v a = *(const float4v*)p;
    float4v b = *(const float4v*)(p + 4);
    ushort_t r[8];
#pragma unroll
    for (int j = 0; j < 4; ++j) { r[j] = f2bf(a[j]); r[4 + j] = f2bf(b[j]); }
    return pack8(r);
}

// ---------- async global->LDS (16B per lane, dest = uniform base + lane*16) ----------
#if __has_builtin(__builtin_amdgcn_global_load_lds)
#define HAVE_GLDS 1
__device__ __forceinline__ void glds16(const ushort_t* gp, ushort_t* lp) {
    __builtin_amdgcn_global_load_lds((const __attribute__((address_space(1))) void*)gp,
                                     (__attribute__((address_space(3))) void*)lp, 16, 0, 0);
}
#else
#define HAVE_GLDS 0
#endif

// ---------- MFMA hedge ----------
template <typename V>
__device__ __forceinline__ auto mfma_sel(V a, V b, float4v c, int)
    -> decltype(__builtin_amdgcn_mfma_f32_16x16x32_bf16(a, b, c, 0, 0, 0)) {
    return __builtin_amdgcn_mfma_f32_16x16x32_bf16(a, b, c, 0, 0, 0);
}
template <typename V>
__device__ __forceinline__ float4v mfma_sel(V a, V b, float4v c, long) {
    return __builtin_amdgcn_mfma_f32_16x16x32_bf16(__builtin_bit_cast(bf16x8, a),
                                                   __builtin_bit_cast(bf16x8, b), c, 0, 0, 0);
}
__device__ __forceinline__ float4v mfma_bf16(short8 a, short8 b, float4v c) {
    return mfma_sel(a, b, c, 0);
}

__device__ __forceinline__ float wave_sum(float v) {
#pragma unroll
    for (int o = 32; o; o >>= 1) v += __shfl_xor(v, o);
    return v;
}

// ---------- constants ----------
#define HIDDEN 2880
#define NTOK 2048
#define QKV_DIM 5120
#define ATTN_DIM 4096
#define SM_SCALE 0.125f

// YaRN rope constants (shared by attn fused rope)
#define ROPE_STEP 0.37244970540869975f   /* 11.918390573078392 / 32 */
#define ROPE_CONC 1.3465735902799727f
#define ROPE_LOW 8.092890725542669f
#define ROPE_INVDEN 0.10745959154836568f /* 1 / 9.305804387286162 */

__device__ __forceinline__ float rope_invfreq(int j) {
    float invf = __expf(-(float)j * ROPE_STEP);
    float ramp = ((float)j - ROPE_LOW) * ROPE_INVDEN;
    float mask = 1.f - fminf(fmaxf(ramp, 0.f), 1.f);
    return invf * ((1.f - mask) * 0.03125f + mask);
}

// ---------- prep: rmsnorm (blocks 0..2047) + fp32->bf16 weight convert (rest) ----------
// r9 lesson: moving out_w conversion into attn as backfill REGRESSED +5.4us - conv
// blocks inherit attn's 77KB LDS allocation, capping residency at 2/CU for all block
// types, so the work serialized through residency instead of overlapping. Both
// conversions stay here (single BW-bound streaming kernel = bandwidth-optimal under
// the sequential-stream constraint).
__global__ __launch_bounds__(256) void prep_kernel(const float* __restrict__ x,
                                                   const float* __restrict__ wgt,
                                                   ushort_t* __restrict__ tout,
                                                   const float* __restrict__ a,
                                                   ushort_t* __restrict__ ao, int na8,
                                                   const float* __restrict__ b,
                                                   ushort_t* __restrict__ bo, int nb8) {
    const int tid = threadIdx.x;
    __shared__ float red[4];
    if (blockIdx.x < NTOK) {
        // ---- RMSNorm for token blockIdx.x ----
        const int tok = blockIdx.x;
        const float* xr = x + (size_t)tok * HIDDEN;
        float v[16];
        float ss = 0.f;
#pragma unroll
        for (int i = 0; i < 2; ++i) {
            int c = tid + i * 256;
            if (c < 360) {
                float4v va = *(const float4v*)(xr + c * 8);
                float4v vb = *(const float4v*)(xr + c * 8 + 4);
#pragma unroll
                for (int j = 0; j < 4; ++j) { v[i * 8 + j] = va[j]; v[i * 8 + 4 + j] = vb[j]; }
#pragma unroll
                for (int j = 0; j < 8; ++j) ss += v[i * 8 + j] * v[i * 8 + j];
            }
        }
        ss = wave_sum(ss);
        if ((tid & 63) == 0) red[tid >> 6] = ss;
        __syncthreads();
        float scale = rsqrtf((red[0] + red[1] + red[2] + red[3]) * (1.f / 2880.f) + 1e-5f);
#pragma unroll
        for (int i = 0; i < 2; ++i) {
            int c = tid + i * 256;
            if (c < 360) {
                float4v wa = *(const float4v*)(wgt + c * 8);
                float4v wb = *(const float4v*)(wgt + c * 8 + 4);
                ushort_t r[8];
#pragma unroll
                for (int j = 0; j < 4; ++j) {
                    r[j] = f2bf(v[i * 8 + j] * scale * wa[j]);
                    r[4 + j] = f2bf(v[i * 8 + 4 + j] * scale * wb[j]);
                }
                *(uint4v*)(tout + (size_t)tok * HIDDEN + c * 8) = pack8(r);
            }
        }
    } else {
        // ---- weight conversion (qkv_w then out_w) ----
        int idx = (blockIdx.x - NTOK) * 256 + tid;
        if (idx < na8) {
            *(uint4v*)(ao + (size_t)idx * 8) = ld8f32_bf(a + (size_t)idx * 8);
        } else {
            int j = idx - na8;
            if (j < nb8) *(uint4v*)(bo + (size_t)j * 8) = ld8f32_bf(b + (size_t)j * 8);
        }
    }
}

// ---------- RMSNorm standalone (fallback path) ----------
__global__ __launch_bounds__(256) void rmsnorm_kernel(const float* __restrict__ x,
                                                      const float* __restrict__ wgt,
                                                      ushort_t* __restrict__ out) {
    const int tok = blockIdx.x, tid = threadIdx.x;
    const float* xr = x + (size_t)tok * HIDDEN;
    float v[16];
    float ss = 0.f;
#pragma unroll
    for (int i = 0; i < 2; ++i) {
        int c = tid + i * 256;
        if (c < 360) {
            float4v a = *(const float4v*)(xr + c * 8);
            float4v b = *(const float4v*)(xr + c * 8 + 4);
#pragma unroll
            for (int j = 0; j < 4; ++j) { v[i * 8 + j] = a[j]; v[i * 8 + 4 + j] = b[j]; }
#pragma unroll
            for (int j = 0; j < 8; ++j) ss += v[i * 8 + j] * v[i * 8 + j];
        }
    }
    ss = wave_sum(ss);
    __shared__ float red[4];
    if ((tid & 63) == 0) red[tid >> 6] = ss;
    __syncthreads();
    float scale = rsqrtf((red[0] + red[1] + red[2] + red[3]) * (1.f / 2880.f) + 1e-5f);
#pragma unroll
    for (int i = 0; i < 2; ++i) {
        int c = tid + i * 256;
        if (c < 360) {
            float4v wa = *(const float4v*)(wgt + c * 8);
            float4v wb = *(const float4v*)(wgt + c * 8 + 4);
            ushort_t r[8];
#pragma unroll
            for (int j = 0; j < 4; ++j) {
                r[j] = f2bf(v[i * 8 + j] * scale * wa[j]);
                r[4 + j] = f2bf(v[i * 8 + 4 + j] * scale * wb[j]);
            }
            *(uint4v*)(out + (size_t)tok * HIDDEN + c * 8) = pack8(r);
        }
    }
}

// ---------- GEMM: C[M,N] = A[M,K](bf16) @ B[N,K]^T + bias (+ resid) ----------
// FROZEN (r8): the 2-phase glds + single-barrier template is a measured local
//   optimum at this geometry. Perturbations all regressed:
//   - counted-vmcnt 2-barrier pipeline (r2): -17%
//   - BN=128 padded-N for better amortization (r3): -11% (residency quantization)
//   - BREG B-direct-to-registers (r8): -2x (116us, MfmaUtil 16%, VALUBusy 7.5%)
//   glds DMA for BOTH operands is strictly best here; do not reintroduce variants.
// Blocks: flattened id XCD-swizzled (T1, bijective since nwg%8==0 for all grids).
// Grid-residency (r3): at 2 blocks/CU capacity, prefer grids just under 512.
template <int BN, bool RESID, bool OUTF32, bool BF16B>
__global__ __launch_bounds__(256) void gemm_kernel(const ushort_t* __restrict__ A,
                                                   const void* __restrict__ B,
                                                   const float* __restrict__ bias,
                                                   const float* __restrict__ resid,
                                                   void* __restrict__ Cout, int M, int N, int K) {
    constexpr int BM = 128, BK = 64;
    constexpr bool GL = BF16B && (HAVE_GLDS != 0);
    constexpr int LDT = GL ? 64 : 72;
    constexpr int NBUF = GL ? 2 : 1;
    static_assert(BN == 160 || BN == 128 || BN == 96 || BN == 64, "");
    __shared__ __align__(16) ushort_t As[NBUF][BM * LDT];
    __shared__ __align__(16) ushort_t Bs[NBUF][BN * LDT];

    // XCD-aware chunked swizzle of the flattened block id (nwg % 8 == 0 for all grids)
    const int nbx = gridDim.x;
    int wg = blockIdx.y * nbx + blockIdx.x;
    {
        const int nwg = nbx * gridDim.y;
        const int cpx = nwg >> 3;
        wg = (wg & 7) * cpx + (wg >> 3);
    }
    const int m0 = (wg / nbx) * BM;
    const int n0 = (wg % nbx) * BN;
    const int tid = threadIdx.x;
    const int w = tid >> 6, lane = tid & 63;
    const int quad = lane >> 4, l16 = lane & 15;

    constexpr int WN = BN / 2;
    constexpr int NI = WN / 16;  // 5 / 4 / 3 / 2
    const int wm = (w >> 1) * 64;
    const int wn = (w & 1) * WN;

    float4v acc[4][NI];
#pragma unroll
    for (int i = 0; i < 4; ++i)
#pragma unroll
        for (int j = 0; j < NI; ++j) acc[i][j] = (float4v){0.f, 0.f, 0.f, 0.f};

    const int nk = K / BK;

#if HAVE_GLDS
    if constexpr (GL) {
        constexpr int NAI = BM / 32;  // glds issues per wave for A
        constexpr int NBI = BN / 32;  // glds issues per wave for B
        const ushort_t* Bp = (const ushort_t*)B;
        const ushort_t* agp[NAI];
        const ushort_t* bgp[NBI];
        ushort_t* alp[2][NAI];
        ushort_t* blp[2][NBI];
#pragma unroll
        for (int i = 0; i < NAI; ++i) {
            int sb = (w * NAI + i) * 64;
            int s = sb + lane, r = s >> 3, p = s & 7, c = p ^ (r & 7);
            agp[i] = A + (size_t)(m0 + r) * K + c * 8;
            alp[0][i] = &As[0][sb * 8];
            alp[1][i] = &As[1][sb * 8];
        }
#pragma unroll
        for (int i = 0; i < NBI; ++i) {
            int sb = (w * NBI + i) * 64;
            int s = sb + lane, r = s >> 3, p = s & 7, c = p ^ (r & 7);
            bgp[i] = Bp + (size_t)(n0 + r) * K + c * 8;
            blp[0][i] = &Bs[0][sb * 8];
            blp[1][i] = &Bs[1][sb * 8];
        }
        // prologue: tile 0 -> buf 0
#pragma unroll
        for (int i = 0; i < NAI; ++i) glds16(agp[i], alp[0][i]);
#pragma unroll
        for (int i = 0; i < NBI; ++i) glds16(bgp[i], blp[0][i]);
        __syncthreads();

        for (int kt = 0; kt < nk; ++kt) {
            const int cur = kt & 1;
            if (kt + 1 < nk) {
                const int k0 = (kt + 1) * BK;
#pragma unroll
                for (int i = 0; i < NAI; ++i) glds16(agp[i] + k0, alp[cur ^ 1][i]);
#pragma unroll
                for (int i = 0; i < NBI; ++i) glds16(bgp[i] + k0, blp[cur ^ 1][i]);
            }
            const ushort_t* Asb = As[cur];
            const ushort_t* Bsb = Bs[cur];
#pragma unroll
            for (int ks = 0; ks < 2; ++ks) {
                short8 af[4], bfr[NI];
#pragma unroll
                for (int mi = 0; mi < 4; ++mi) {
                    int row = wm + mi * 16 + l16;
                    af[mi] = *(const short8*)(Asb + row * LDT + ((ks * 4 + quad) ^ (row & 7)) * 8);
                }
#pragma unroll
                for (int ni = 0; ni < NI; ++ni) {
                    int row = wn + ni * 16 + l16;
                    bfr[ni] = *(const short8*)(Bsb + row * LDT + ((ks * 4 + quad) ^ (row & 7)) * 8);
                }
#pragma unroll
                for (int mi = 0; mi < 4; ++mi)
#pragma unroll
                    for (int ni = 0; ni < NI; ++ni)
                        acc[mi][ni] = mfma_bf16(af[mi], bfr[ni], acc[mi][ni]);
            }
            __syncthreads();
        }
    } else
#endif
    {
        // fallback: padded LDS + register prefetch (round-5 structure)
        constexpr int ACH = BM * BK / 8 / 256;
        constexpr int BCH = BN * BK / 8 / 256;
        uint4v areg[ACH], breg[BCH];
#pragma unroll
        for (int i = 0; i < ACH; ++i) {
            int c = tid + i * 256, r = c >> 3, col = c & 7;
            areg[i] = *(const uint4v*)(A + (size_t)(m0 + r) * K + col * 8);
        }
#pragma unroll
        for (int i = 0; i < BCH; ++i) {
            int c = tid + i * 256, r = c >> 3, col = c & 7;
            if constexpr (BF16B)
                breg[i] = *(const uint4v*)((const ushort_t*)B + (size_t)(n0 + r) * K + col * 8);
            else
                breg[i] = ld8f32_bf((const float*)B + (size_t)(n0 + r) * K + col * 8);
        }
        for (int kt = 0; kt < nk; ++kt) {
            __syncthreads();
#pragma unroll
            for (int i = 0; i < ACH; ++i) {
                int c = tid + i * 256, r = c >> 3, col = c & 7;
                *(uint4v*)(&As[0][r * LDT + col * 8]) = areg[i];
            }
#pragma unroll
            for (int i = 0; i < BCH; ++i) {
                int c = tid + i * 256, r = c >> 3, col = c & 7;
                *(uint4v*)(&Bs[0][(size_t)r * LDT + col * 8]) = breg[i];
            }
            __syncthreads();
            if (kt + 1 < nk) {
                const int k0 = (kt + 1) * BK;
#pragma unroll
                for (int i = 0; i < ACH; ++i) {
                    int c = tid + i * 256, r = c >> 3, col = c & 7;
                    areg[i] = *(const uint4v*)(A + (size_t)(m0 + r) * K + k0 + col * 8);
                }
#pragma unroll
                for (int i = 0; i < BCH; ++i) {
                    int c = tid + i * 256, r = c >> 3, col = c & 7;
                    if constexpr (BF16B)
                        breg[i] = *(const uint4v*)((const ushort_t*)B + (size_t)(n0 + r) * K + k0 + col * 8);
                    else
                        breg[i] = ld8f32_bf((const float*)B + (size_t)(n0 + r) * K + k0 + col * 8);
                }
            }
#pragma unroll
            for (int ks = 0; ks < 2; ++ks) {
                short8 af[4], bfr[NI];
#pragma unroll
                for (int mi = 0; mi < 4; ++mi)
                    af[mi] = *(const short8*)(&As[0][(wm + mi * 16 + l16) * LDT + ks * 32 + quad * 8]);
#pragma unroll
                for (int ni = 0; ni < NI; ++ni)
                    bfr[ni] = *(const short8*)(&Bs[0][(size_t)(wn + ni * 16 + l16) * LDT + ks * 32 + quad * 8]);
#pragma unroll
                for (int mi = 0; mi < 4; ++mi)
#pragma unroll
                    for (int ni = 0; ni < NI; ++ni)
                        acc[mi][ni] = mfma_bf16(af[mi], bfr[ni], acc[mi][ni]);
            }
        }
    }

    // epilogue: C/D layout col = lane&15, row = quad*4 + reg
#pragma unroll
    for (int ni = 0; ni < NI; ++ni) {
        int gc = n0 + wn + ni * 16 + l16;
        float bv = bias[gc];
#pragma unroll
        for (int mi = 0; mi < 4; ++mi) {
#pragma unroll
            for (int r = 0; r < 4; ++r) {
                int gr = m0 + wm + mi * 16 + quad * 4 + r;
                float vv = acc[mi][ni][r] + bv;
                if constexpr (RESID) vv += resid[(size_t)gr * N + gc];
                if constexpr (OUTF32) ((float*)Cout)[(size_t)gr * N + gc] = vv;
                else ((ushort_t*)Cout)[(size_t)gr * N + gc] = f2bf(vv);
            }
        }
    }
}

// ---------- MFMA attention: sliding window 128 + sink, RoPE fused on load ----------
// Grid (qc 16, kvh*2+half 16, b 2) = 512 blocks, 2 blocks/CU (~77KB LDS).
// Wave w handles head kvh*8 + half*4 + w, 4 query-tiles of 16.
// RoPE fusion (r6): qkvbuf is UN-roped; q/k regions are consumed only here.
//   Q: rotate-half pair (d, d+32) = (qf[0][jj], qf[1][jj]) -> same lane, rope is
//      lane-local at load; inv_freq(quad*8+jj) hoisted per lane.
//   K: staging restructured so each lane loads dims [col4*8,+8) AND [+32,+8) of one
//      row, ropes 8 pairs (inv_freq((tid&3)*8+jj) hoisted - iteration-invariant),
//      writes both 16B chunks. OOB-clamped rows get roped at clamped pos - fully
//      masked downstream. V needs no rope.
// Window-aware compute: q-tile qtile touches key-tiles qtile..qtile+8 and PV slices
//   kt = (qtile>>1)..+4. Pair structure: q-tiles (2p,2p+1) share Vf[5][4] hoist.
// r9 lesson: do NOT add heterogeneous backfill blocks here - they inherit this
//   kernel's LDS allocation and throttle residency (+5.4us measured).
__global__ __launch_bounds__(256, 2) void attn_mfma_kernel(const ushort_t* __restrict__ qkv,
                                                           const float* __restrict__ sinks,
                                                           ushort_t* __restrict__ attnbuf) {
    constexpr int LDK = 72, LDV = 200, LDP = 200;
    __shared__ __align__(16) ushort_t Ks[192 * LDK];
    __shared__ __align__(16) ushort_t Vt[64 * LDV];
    __shared__ __align__(16) ushort_t Pb[4][16 * LDP];

    const int qc = blockIdx.x, kvh = blockIdx.y >> 1, half = blockIdx.y & 1, b = blockIdx.z;
    const int tid = threadIdx.x;
    const int w = tid >> 6, lane = tid & 63;
    const int quad = lane >> 4, l16 = lane & 15;
    const int w0 = qc * 64 - 127;  // key position of LDS row 0

    // K stage + rope: 3 iters; lane owns dims [col4*8,+8) and [+32,+8) of row c>>2.
    {
        float invfK[8];
#pragma unroll
        for (int jj = 0; jj < 8; ++jj) invfK[jj] = rope_invfreq((tid & 3) * 8 + jj);
        for (int c = tid; c < 192 * 4; c += 256) {
            int row = c >> 2, col4 = c & 3;
            int pos = w0 + row;
            pos = pos < 0 ? 0 : (pos > 1023 ? 1023 : pos);
            size_t gk = ((size_t)(b * 1024 + pos)) * QKV_DIM + 4096 + kvh * 64 + col4 * 8;
            uint4v u1 = *(const uint4v*)(qkv + gk);
            uint4v u2 = *(const uint4v*)(qkv + gk + 32);
            float f1[8], f2[8];
            unpack8(u1, f1);
            unpack8(u2, f2);
            float s = (float)pos;
            ushort_t r1[8], r2[8];
#pragma unroll
            for (int jj = 0; jj < 8; ++jj) {
                float ang = s * invfK[jj];
                float cc = __cosf(ang) * ROPE_CONC;
                float sn = __sinf(ang) * ROPE_CONC;
                r1[jj] = f2bf(f1[jj] * cc - f2[jj] * sn);
                r2[jj] = f2bf(f2[jj] * cc + f1[jj] * sn);
            }
            *(uint4v*)(Ks + row * LDK + col4 * 8) = pack8(r1);
            *(uint4v*)(Ks + row * LDK + (col4 + 4) * 8) = pack8(r2);
        }
    }
    // V stage (transpose), no rope
    for (int c = tid; c < 192 * 8; c += 256) {
        int row = c >> 3, col8 = c & 7;
        int pos = w0 + row;
        pos = pos < 0 ? 0 : (pos > 1023 ? 1023 : pos);
        size_t gv = ((size_t)(b * 1024 + pos)) * QKV_DIM + 4608 + kvh * 64 + col8 * 8;
        uint4v vv = *(const uint4v*)(qkv + gv);
        ushort_t vs[8];
#pragma unroll
        for (int i = 0; i < 4; ++i) {
            vs[2 * i] = (ushort_t)(vv[i] & 0xffffu);
            vs[2 * i + 1] = (ushort_t)(vv[i] >> 16);
        }
#pragma unroll
        for (int j = 0; j < 8; ++j) Vt[(col8 * 8 + j) * LDV + row] = vs[j];
    }
    __syncthreads();

    ushort_t* Pw = Pb[w];
    const int h = kvh * 8 + half * 4 + w;
    const float sink_f = sinks[h];

    // per-lane Q rope inv_freq: j = quad*8+jj
    float invfQ[8];
#pragma unroll
    for (int jj = 0; jj < 8; ++jj) invfQ[jj] = rope_invfreq(quad * 8 + jj);

    for (int p = 0; p < 2; ++p) {  // q-tile pair: q-tiles 2p, 2p+1 share PV kt = p..p+4
        short8 Vf[5][4];
#pragma unroll
        for (int j = 0; j < 5; ++j)
#pragma unroll
            for (int nv = 0; nv < 4; ++nv)
                Vf[j][nv] = *(const short8*)(Vt + (nv * 16 + l16) * LDV + (p + j) * 32 + quad * 8);

#pragma unroll
        for (int qq = 0; qq < 2; ++qq) {
            const int qtile = 2 * p + qq;
            const int tokb = b * 1024 + qc * 64 + qtile * 16;

            // Q load + lane-local rope
            short8 qf[2];
            {
                const ushort_t* qp = qkv + ((size_t)(tokb + l16)) * QKV_DIM + h * 64 + quad * 8;
                uint4v u1 = *(const uint4v*)qp;
                uint4v u2 = *(const uint4v*)(qp + 32);
                float f1[8], f2[8];
                unpack8(u1, f1);
                unpack8(u2, f2);
                float s = (float)((tokb + l16) & 1023);
                ushort_t r1[8], r2[8];
#pragma unroll
                for (int jj = 0; jj < 8; ++jj) {
                    float ang = s * invfQ[jj];
                    float cc = __cosf(ang) * ROPE_CONC;
                    float sn = __sinf(ang) * ROPE_CONC;
                    r1[jj] = f2bf(f1[jj] * cc - f2[jj] * sn);
                    r2[jj] = f2bf(f2[jj] * cc + f1[jj] * sn);
                }
                qf[0] = __builtin_bit_cast(short8, pack8(r1));
                qf[1] = __builtin_bit_cast(short8, pack8(r2));
            }

            // QK^T over the 9 valid key-tiles (nt = qtile + j)
            float4v acc[9];
#pragma unroll
            for (int j = 0; j < 9; ++j) acc[j] = (float4v){0.f, 0.f, 0.f, 0.f};
            __builtin_amdgcn_s_setprio(1);
#pragma unroll
            for (int j = 0; j < 9; ++j) {
                const int nt = qtile + j;
#pragma unroll
                for (int ks = 0; ks < 2; ++ks) {
                    short8 kf = *(const short8*)(Ks + (nt * 16 + l16) * LDK + ks * 32 + quad * 8);
                    acc[j] = mfma_bf16(qf[ks], kf, acc[j]);
                }
            }
            __builtin_amdgcn_s_setprio(0);

            // P tile to zero so PV's nt range [2p, 2p+9] reads only written/zeroed data
            const int ntz = qq ? (qtile - 1) : (qtile + 9);

            float linv[4];
#pragma unroll
            for (int r = 0; r < 4; ++r) {
                const int ql = qtile * 16 + quad * 4 + r;
                float e[9];
                float mx = -1e30f;
#pragma unroll
                for (int j = 0; j < 9; ++j) {
                    int row_k = (qtile + j) * 16 + l16;
                    bool valid = (row_k >= ql) && (row_k <= ql + 127) && (w0 + row_k >= 0);
                    float s = valid ? acc[j][r] * SM_SCALE : -1e30f;
                    e[j] = s;
                    mx = fmaxf(mx, s);
                }
#pragma unroll
                for (int o = 1; o < 16; o <<= 1) mx = fmaxf(mx, __shfl_xor(mx, o));
                float M = fmaxf(mx, sink_f);
                float ls = 0.f;
#pragma unroll
                for (int j = 0; j < 9; ++j) {
                    float ev = (e[j] > -1e29f) ? __expf(e[j] - M) : 0.f;
                    e[j] = ev;
                    ls += ev;
                }
#pragma unroll
                for (int o = 1; o < 16; o <<= 1) ls += __shfl_xor(ls, o);
                linv[r] = 1.f / (ls + __expf(sink_f - M));
#pragma unroll
                for (int j = 0; j < 9; ++j)
                    Pw[(quad * 4 + r) * LDP + (qtile + j) * 16 + l16] = f2bf(e[j]);
                Pw[(quad * 4 + r) * LDP + ntz * 16 + l16] = 0;
            }

            // PV over the 5 valid k-slices (kt = p + j, matching Vf[j])
            float4v accO[4];
#pragma unroll
            for (int nv = 0; nv < 4; ++nv) accO[nv] = (float4v){0.f, 0.f, 0.f, 0.f};
            __builtin_amdgcn_s_setprio(1);
#pragma unroll
            for (int j = 0; j < 5; ++j) {
                short8 pf = *(const short8*)(Pw + l16 * LDP + (p + j) * 32 + quad * 8);
#pragma unroll
                for (int nv = 0; nv < 4; ++nv) accO[nv] = mfma_bf16(pf, Vf[j][nv], accO[nv]);
            }
            __builtin_amdgcn_s_setprio(0);

#pragma unroll
            for (int r = 0; r < 4; ++r) {
                size_t ob = ((size_t)(tokb + quad * 4 + r)) * ATTN_DIM + h * 64 + l16;
#pragma unroll
                for (int nv = 0; nv < 4; ++nv)
                    attnbuf[ob + nv * 16] = f2bf(accO[nv][r] * linv[r]);
            }
        }
    }
}

// ---------- launch ----------
extern "C" void kernel_launch(void* const* d_in, const int* in_sizes, int n_in,
                              void* d_out, int out_size, void* d_ws, size_t ws_size,
                              hipStream_t stream) {
    const float* x = (const float*)d_in[0];
    const float* norm_w = (const float*)d_in[1];
    const float* qkv_w = (const float*)d_in[2];
    const float* qkv_b = (const float*)d_in[3];
    const float* out_w = (const float*)d_in[4];
    const float* out_b = (const float*)d_in[5];
    const float* sinks = (const float*)d_in[6];
    float* outp = (float*)d_out;
    char* ws = (char*)d_ws;

    if (ws_size >= 86000000ull) {
        // ws: qkvbuf 21MB | {qkv_w_bf 29.5MB -> attnbuf 16.8MB} | out_w_bf 23.6MB
        // Tbuf lives in d_out (dead before GEMM2 overwrites d_out).
        ushort_t* qkvbuf = (ushort_t*)ws;
        ushort_t* qkv_w_bf = (ushort_t*)(ws + 20971520);
        ushort_t* attnbuf = (ushort_t*)(ws + 20971520);  // reuse after gemm1 consumed qkv_w_bf
        ushort_t* out_w_bf = (ushort_t*)(ws + 50462720);
        ushort_t* Tbuf = (ushort_t*)d_out;

        // prep: 2048 rmsnorm blocks + 12960 conversion blocks in one launch
        prep_kernel<<<NTOK + 12960, 256, 0, stream>>>(x, norm_w, Tbuf, qkv_w, qkv_w_bf,
                                                      1843200, out_w, out_w_bf, 1474560);
        gemm_kernel<160, false, false, true><<<dim3(32, 16), 256, 0, stream>>>(
            Tbuf, qkv_w_bf, qkv_b, nullptr, qkvbuf, NTOK, QKV_DIM, HIDDEN);
        attn_mfma_kernel<<<dim3(16, 16, 2), 256, 0, stream>>>(qkvbuf, sinks, attnbuf);
        gemm_kernel<96, true, true, true><<<dim3(30, 16), 256, 0, stream>>>(
            attnbuf, out_w_bf, out_b, x, outp, NTOK, HIDDEN, ATTN_DIM);
    } else {
        // fallback: fp32 B loads (register staging), Tbuf in d_out
        ushort_t* qkvbuf = (ushort_t*)ws;
        ushort_t* attnbuf = (ushort_t*)(ws + 20971520);
        ushort_t* Tbuf = (ushort_t*)d_out;

        rmsnorm_kernel<<<NTOK, 256, 0, stream>>>(x, norm_w, Tbuf);
        gemm_kernel<128, false, false, false><<<dim3(40, 16), 256, 0, stream>>>(
            Tbuf, qkv_w, qkv_b, nullptr, qkvbuf, NTOK, QKV_DIM, HIDDEN);
        attn_mfma_kernel<<<dim3(16, 16, 2), 256, 0, stream>>>(qkvbuf, sinks, attnbuf);
        gemm_kernel<96, true, true, false><<<dim3(30, 16), 256, 0, stream>>>(
            attnbuf, out_w, out_b, x, outp, NTOK, HIDDEN, ATTN_DIM);
    }
}